// Round 2
// baseline (179.672 us; speedup 1.0000x reference)
//
#include <hip/hip_runtime.h>
#include <hip/hip_bf16.h>

// B=4, T=2048, SD=64, NE=4096, H=8, HS=8, FH=256. All reference reshapes are
// flat reinterpretations, so one flat buffer serves every "view".
// h/y/qc flat element (t,l): b*131072 + t*64 + l.
// x viewed (B,SD,SD,T): b*4194304 + i*131072 + j*2048 + t.
// out viewed (B,SD,SD,T): b*8388608 + i*131072 + j*2048 + t.

#define EPSF 1e-5f

__device__ __forceinline__ unsigned fkey(float m) {
    unsigned u = __float_as_uint(m);
    return (u & 0x80000000u) ? ~u : (u | 0x80000000u);
}
__device__ __forceinline__ float fdec(unsigned u) {
    unsigned bits = (u & 0x80000000u) ? (u ^ 0x80000000u) : ~u;
    return __uint_as_float(bits);
}

// ------ K1: Feebler + LayerNorm1 + column-sum of y --------------------------
// Block (b,i): 512 threads, each owns one float4 (4 cols of one LN row).
// Block covers flat rows [i*32, i*32+32) of the (t,l) view.
__global__ void K1(const float* __restrict__ x, const float* __restrict__ fw,
                   const float* __restrict__ g, const float* __restrict__ bia,
                   float* __restrict__ h, float* __restrict__ y,
                   float* __restrict__ ysum) {
    int b = blockIdx.x >> 6, i = blockIdx.x & 63;
    int t4 = threadIdx.x;                       // 0..511
    const float4* x4 = (const float4*)x + (size_t)b * 2097152 + (size_t)i * 32768 + t4;
    const float4* f4 = (const float4*)fw + (size_t)i * 32768 + t4;
    float4 acc = make_float4(0.f, 0.f, 0.f, 0.f);
    #pragma unroll 8
    for (int j = 0; j < 64; ++j) {
        float4 xv = x4[(size_t)j * 512];
        float4 fv = f4[(size_t)j * 512];
        acc.x += xv.x * fv.x; acc.y += xv.y * fv.y;
        acc.z += xv.z * fv.z; acc.w += xv.w * fv.w;
    }
    // LN over the 64-col row: 16 threads per row, all in one wave.
    float s1 = acc.x + acc.y + acc.z + acc.w;
    float s2 = acc.x * acc.x + acc.y * acc.y + acc.z * acc.z + acc.w * acc.w;
    for (int off = 8; off; off >>= 1) {
        s1 += __shfl_xor(s1, off);
        s2 += __shfl_xor(s2, off);
    }
    float m = s1 * (1.f / 64.f);
    float var = s2 * (1.f / 64.f) - m * m;
    float rs = rsqrtf(var + EPSF);
    float4 gv = ((const float4*)g)[t4 & 15];
    float4 bv = ((const float4*)bia)[t4 & 15];
    float4 yv;
    yv.x = (acc.x - m) * rs * gv.x + bv.x;
    yv.y = (acc.y - m) * rs * gv.y + bv.y;
    yv.z = (acc.z - m) * rs * gv.z + bv.z;
    yv.w = (acc.w - m) * rs * gv.w + bv.w;
    size_t oidx = (size_t)b * 32768 + (size_t)i * 512 + t4;
    ((float4*)h)[oidx] = acc;
    ((float4*)y)[oidx] = yv;
    // column sums (32 rows in this block)
    __shared__ float ysL[64];
    if (threadIdx.x < 64) ysL[threadIdx.x] = 0.f;
    __syncthreads();
    int c0 = (t4 & 15) * 4;
    atomicAdd(&ysL[c0 + 0], yv.x);
    atomicAdd(&ysL[c0 + 1], yv.y);
    atomicAdd(&ysL[c0 + 2], yv.z);
    atomicAdd(&ysL[c0 + 3], yv.w);
    __syncthreads();
    if (threadIdx.x < 64) atomicAdd(&ysum[b * 64 + threadIdx.x], ysL[threadIdx.x]);
}

// ------ K2: ck (inline from ysum) + qc = (y@Wq)*ck + column max -------------
__global__ void K2(const float* __restrict__ y, const float* __restrict__ wq,
                   const float* __restrict__ wk, const float* __restrict__ ysum,
                   float* __restrict__ qc, unsigned* __restrict__ umax) {
    __shared__ float yT[64][68];      // yT[s][r] = y[t0+r][s], padded
    __shared__ float wqL[64][64];     // wqL[s][c]
    __shared__ float pmax[4][64];
    int b = blockIdx.x, t0 = blockIdx.y * 64;
    int tid = threadIdx.x;
    for (int kk = 0; kk < 16; ++kk) {
        int idx = kk * 256 + tid;
        int r = idx >> 6, cc = idx & 63;
        yT[cc][r] = y[(size_t)b * 131072 + (size_t)(t0 + r) * 64 + cc];
        wqL[r][cc] = wq[(cc >> 3) * 512 + r * 8 + (cc & 7)];
    }
    __syncthreads();
    int c = tid & 63, tq = tid >> 6;
    float ck = 0.f;
    for (int s = 0; s < 64; ++s)
        ck += ysum[b * 64 + s] * wk[(c >> 3) * 512 + s * 8 + (c & 7)];
    float acc[16];
    #pragma unroll
    for (int k = 0; k < 16; ++k) acc[k] = 0.f;
    for (int s = 0; s < 64; ++s) {
        float w = wqL[s][c];
        const float4* yp = (const float4*)&yT[s][tq * 16];
        float4 a0 = yp[0], a1 = yp[1], a2 = yp[2], a3 = yp[3];
        acc[0]  += a0.x * w; acc[1]  += a0.y * w; acc[2]  += a0.z * w; acc[3]  += a0.w * w;
        acc[4]  += a1.x * w; acc[5]  += a1.y * w; acc[6]  += a1.z * w; acc[7]  += a1.w * w;
        acc[8]  += a2.x * w; acc[9]  += a2.y * w; acc[10] += a2.z * w; acc[11] += a2.w * w;
        acc[12] += a3.x * w; acc[13] += a3.y * w; acc[14] += a3.z * w; acc[15] += a3.w * w;
    }
    float lmax = -3.4e38f;
    #pragma unroll
    for (int k = 0; k < 16; ++k) {
        float v = acc[k] * ck;
        qc[(size_t)b * 131072 + (size_t)(t0 + tq * 16 + k) * 64 + c] = v;
        lmax = fmaxf(lmax, v);
    }
    pmax[tq][c] = lmax;
    __syncthreads();
    if (tid < 64) {
        float m = fmaxf(fmaxf(pmax[0][tid], pmax[1][tid]),
                        fmaxf(pmax[2][tid], pmax[3][tid]));
        atomicMax(&umax[b * 64 + tid], fkey(m));
    }
}

// ------ K3: denom[b,c] = sum_t exp(qc - m) ----------------------------------
__global__ void K3(const float* __restrict__ qc, const unsigned* __restrict__ umax,
                   float* __restrict__ denom) {
    __shared__ float psum[4][64];
    int b = blockIdx.x, t0 = blockIdx.y * 64;
    int tid = threadIdx.x, c = tid & 63, tq = tid >> 6;
    float m = fdec(umax[b * 64 + c]);
    float ls = 0.f;
    #pragma unroll 4
    for (int k = 0; k < 16; ++k)
        ls += __expf(qc[(size_t)b * 131072 + (size_t)(t0 + tq * 16 + k) * 64 + c] - m);
    psum[tq][c] = ls;
    __syncthreads();
    if (tid < 64)
        atomicAdd(&denom[b * 64 + tid],
                  psum[0][tid] + psum[1][tid] + psum[2][tid] + psum[3][tid]);
}

// ------ K4: sa=(e*cv/den)@projw+projb; +h; LN2; FFN; +; Booster -> out ------
// Block (b,j): 32 t-rows == flat chunk j of the (SD,T) view. Writes out directly.
__global__ void K4(const float* __restrict__ h, const float* __restrict__ qc,
                   const float* __restrict__ ysum, const unsigned* __restrict__ umax,
                   const float* __restrict__ denom, const float* __restrict__ wv,
                   const float* __restrict__ projw, const float* __restrict__ projb,
                   const float* __restrict__ g2, const float* __restrict__ b2l,
                   const float* __restrict__ w1, const float* __restrict__ b1,
                   const float* __restrict__ w2, const float* __restrict__ fb2,
                   const float* __restrict__ bw, float* __restrict__ out) {
    __shared__ float pT[4][64][8];     // pT[w][c][rr]
    __shared__ float y2T[4][64][8];    // y2T[w][s][rr]
    __shared__ float hidT[4][256][8];  // hidT[w][j][rr]
    __shared__ float hfL[2048];
    int b = blockIdx.x, j = blockIdx.y;
    int tid = threadIdx.x, l = tid & 63, w = tid >> 6;

    float cv = 0.f;
    for (int s = 0; s < 64; ++s)
        cv += ysum[b * 64 + s] * wv[(l >> 3) * 512 + s * 8 + (l & 7)];
    float m = fdec(umax[b * 64 + l]);
    float scl = cv / denom[b * 64 + l];
    size_t base = (size_t)b * 131072 + (size_t)(j * 32 + w * 8) * 64 + l;

    float p[8];
    #pragma unroll
    for (int rr = 0; rr < 8; ++rr)
        p[rr] = __expf(qc[base + rr * 64] - m) * scl;
    *(float4*)&pT[w][l][0] = make_float4(p[0], p[1], p[2], p[3]);
    *(float4*)&pT[w][l][4] = make_float4(p[4], p[5], p[6], p[7]);
    __syncthreads();

    // proj
    float a[8];
    #pragma unroll
    for (int rr = 0; rr < 8; ++rr) a[rr] = 0.f;
    for (int c = 0; c < 64; ++c) {
        float4 p0 = *(const float4*)&pT[w][c][0];
        float4 p1 = *(const float4*)&pT[w][c][4];
        float pw = projw[c * 64 + l];
        a[0] += p0.x * pw; a[1] += p0.y * pw; a[2] += p0.z * pw; a[3] += p0.w * pw;
        a[4] += p1.x * pw; a[5] += p1.y * pw; a[6] += p1.z * pw; a[7] += p1.w * pw;
    }
    float pb = projb[l], g2v = g2[l], b2v = b2l[l];
    float hmid[8], y2[8];
    #pragma unroll
    for (int rr = 0; rr < 8; ++rr) {
        hmid[rr] = h[base + rr * 64] + a[rr] + pb;
        float v = hmid[rr];
        float s1 = v, s2 = v * v;
        for (int off = 32; off; off >>= 1) {
            s1 += __shfl_xor(s1, off);
            s2 += __shfl_xor(s2, off);
        }
        float mm = s1 * (1.f / 64.f);
        float var = s2 * (1.f / 64.f) - mm * mm;
        float rs = rsqrtf(var + EPSF);
        y2[rr] = (v - mm) * rs * g2v + b2v;
    }
    *(float4*)&y2T[w][l][0] = make_float4(y2[0], y2[1], y2[2], y2[3]);
    *(float4*)&y2T[w][l][4] = make_float4(y2[4], y2[5], y2[6], y2[7]);
    __syncthreads();

    // FFN1
    float h1[4][8];
    #pragma unroll
    for (int u = 0; u < 4; ++u) {
        float bb = b1[u * 64 + l];
        #pragma unroll
        for (int rr = 0; rr < 8; ++rr) h1[u][rr] = bb;
    }
    for (int s = 0; s < 64; ++s) {
        float4 y0 = *(const float4*)&y2T[w][s][0];
        float4 y1 = *(const float4*)&y2T[w][s][4];
        #pragma unroll
        for (int u = 0; u < 4; ++u) {
            float w1v = w1[s * 256 + u * 64 + l];
            h1[u][0] += y0.x * w1v; h1[u][1] += y0.y * w1v;
            h1[u][2] += y0.z * w1v; h1[u][3] += y0.w * w1v;
            h1[u][4] += y1.x * w1v; h1[u][5] += y1.y * w1v;
            h1[u][6] += y1.z * w1v; h1[u][7] += y1.w * w1v;
        }
    }
    #pragma unroll
    for (int u = 0; u < 4; ++u) {
        *(float4*)&hidT[w][u * 64 + l][0] = make_float4(
            fmaxf(h1[u][0], 0.f), fmaxf(h1[u][1], 0.f),
            fmaxf(h1[u][2], 0.f), fmaxf(h1[u][3], 0.f));
        *(float4*)&hidT[w][u * 64 + l][4] = make_float4(
            fmaxf(h1[u][4], 0.f), fmaxf(h1[u][5], 0.f),
            fmaxf(h1[u][6], 0.f), fmaxf(h1[u][7], 0.f));
    }
    __syncthreads();

    // FFN2 + residual -> hfL
    float a2[8];
    #pragma unroll
    for (int rr = 0; rr < 8; ++rr) a2[rr] = 0.f;
    for (int jj = 0; jj < 256; ++jj) {
        float4 h0 = *(const float4*)&hidT[w][jj][0];
        float4 h4 = *(const float4*)&hidT[w][jj][4];
        float w2v = w2[jj * 64 + l];
        a2[0] += h0.x * w2v; a2[1] += h0.y * w2v; a2[2] += h0.z * w2v; a2[3] += h0.w * w2v;
        a2[4] += h4.x * w2v; a2[5] += h4.y * w2v; a2[6] += h4.z * w2v; a2[7] += h4.w * w2v;
    }
    float fb = fb2[l];
    #pragma unroll
    for (int rr = 0; rr < 8; ++rr)
        hfL[(w * 8 + rr) * 64 + l] = hmid[rr] + a2[rr] + fb;
    __syncthreads();

    // Booster: out[b,i,j,t'] = bw[i,j,t'] * hfL[t']
    float4 hr0 = *(const float4*)&hfL[tid * 8];
    float4 hr1 = *(const float4*)&hfL[tid * 8 + 4];
    const float* bwb = bw + (size_t)j * 2048 + tid * 8;
    float* ob = out + (size_t)b * 8388608 + (size_t)j * 2048 + tid * 8;
    for (int i = 0; i < 64; ++i) {
        float4 w0 = *(const float4*)&bwb[(size_t)i * 131072];
        float4 w4 = *(const float4*)&bwb[(size_t)i * 131072 + 4];
        float4 o0, o1;
        o0.x = w0.x * hr0.x; o0.y = w0.y * hr0.y; o0.z = w0.z * hr0.z; o0.w = w0.w * hr0.w;
        o1.x = w4.x * hr1.x; o1.y = w4.y * hr1.y; o1.z = w4.z * hr1.z; o1.w = w4.w * hr1.w;
        *(float4*)&ob[(size_t)i * 131072] = o0;
        *(float4*)&ob[(size_t)i * 131072 + 4] = o1;
    }
}

extern "C" void kernel_launch(void* const* d_in, const int* in_sizes, int n_in,
                              void* d_out, int out_size, void* d_ws, size_t ws_size,
                              hipStream_t stream) {
    const float* x     = (const float*)d_in[0];
    const float* fw    = (const float*)d_in[1];
    const float* bw    = (const float*)d_in[2];
    const float* wq    = (const float*)d_in[3];
    const float* wk    = (const float*)d_in[4];
    const float* wv    = (const float*)d_in[5];
    const float* projw = (const float*)d_in[6];
    const float* projb = (const float*)d_in[7];
    const float* g1    = (const float*)d_in[8];
    const float* b1l   = (const float*)d_in[9];
    const float* g2    = (const float*)d_in[10];
    const float* b2l   = (const float*)d_in[11];
    const float* w1    = (const float*)d_in[12];
    const float* b1    = (const float*)d_in[13];
    const float* w2    = (const float*)d_in[14];
    const float* b2    = (const float*)d_in[15];
    float* out = (float*)d_out;

    float* wsf = (float*)d_ws;
    float*    h     = wsf;                 // 524288
    float*    y     = wsf + 524288;        // 524288
    float*    qc    = wsf + 1048576;       // 524288
    float*    ysum  = wsf + 1572864;       // 256
    unsigned* um    = (unsigned*)(wsf + 1573120); // 256
    float*    denom = wsf + 1573376;       // 256

    hipMemsetAsync(ysum, 0, 768 * sizeof(float), stream);

    K1<<<256, 512, 0, stream>>>(x, fw, g1, b1l, h, y, ysum);
    K2<<<dim3(4, 32), 256, 0, stream>>>(y, wq, wk, ysum, qc, um);
    K3<<<dim3(4, 32), 256, 0, stream>>>(qc, um, denom);
    K4<<<dim3(4, 64), 256, 0, stream>>>(h, qc, ysum, um, denom, wv, projw, projb,
                                        g2, b2l, w1, b1, w2, b2, bw, out);
}

// Round 3
// 139.339 us; speedup vs baseline: 1.2895x; 1.2895x over previous
//
#include <hip/hip_runtime.h>
#include <hip/hip_bf16.h>

// B=4, T=2048, SD=64, NE=4096, H=8, HS=8, FH=256. All reference reshapes are
// flat reinterpretations, so one flat buffer serves every "view".
// h/y/qc/hf flat element (t,l): b*131072 + t*64 + l.
// x viewed (B,SD,SD,T): b*4194304 + i*131072 + j*2048 + t.
// out viewed (B,SD,SD,T): b*8388608 + i*131072 + j*2048 + t.

#define EPSF 1e-5f

__device__ __forceinline__ unsigned fkey(float m) {
    unsigned u = __float_as_uint(m);
    return (u & 0x80000000u) ? ~u : (u | 0x80000000u);
}
__device__ __forceinline__ float fdec(unsigned u) {
    unsigned bits = (u & 0x80000000u) ? (u ^ 0x80000000u) : ~u;
    return __uint_as_float(bits);
}

// ------ K1: Feebler + LayerNorm1 + column-sum of y --------------------------
// Block (b,i,tchunk): 256 threads, each owns one float4 (4 cols of one LN row).
__global__ void K1(const float* __restrict__ x, const float* __restrict__ fw,
                   const float* __restrict__ g, const float* __restrict__ bia,
                   float* __restrict__ h, float* __restrict__ y,
                   float* __restrict__ ysum) {
    int b = blockIdx.x >> 6, i = blockIdx.x & 63;
    int t4 = blockIdx.y * 256 + threadIdx.x;    // 0..511 float4 idx in this (b,i)
    const float4* x4 = (const float4*)x + (size_t)b * 2097152 + (size_t)i * 32768 + t4;
    const float4* f4 = (const float4*)fw + (size_t)i * 32768 + t4;
    float4 acc = make_float4(0.f, 0.f, 0.f, 0.f);
    #pragma unroll 8
    for (int j = 0; j < 64; ++j) {
        float4 xv = x4[(size_t)j * 512];
        float4 fv = f4[(size_t)j * 512];
        acc.x += xv.x * fv.x; acc.y += xv.y * fv.y;
        acc.z += xv.z * fv.z; acc.w += xv.w * fv.w;
    }
    // LN over the 64-col row: 16 consecutive threads per row (same wave).
    float s1 = acc.x + acc.y + acc.z + acc.w;
    float s2 = acc.x * acc.x + acc.y * acc.y + acc.z * acc.z + acc.w * acc.w;
    for (int off = 8; off; off >>= 1) {
        s1 += __shfl_xor(s1, off);
        s2 += __shfl_xor(s2, off);
    }
    float m = s1 * (1.f / 64.f);
    float var = s2 * (1.f / 64.f) - m * m;
    float rs = rsqrtf(var + EPSF);
    float4 gv = ((const float4*)g)[t4 & 15];
    float4 bv = ((const float4*)bia)[t4 & 15];
    float4 yv;
    yv.x = (acc.x - m) * rs * gv.x + bv.x;
    yv.y = (acc.y - m) * rs * gv.y + bv.y;
    yv.z = (acc.z - m) * rs * gv.z + bv.z;
    yv.w = (acc.w - m) * rs * gv.w + bv.w;
    size_t oidx = (size_t)b * 32768 + (size_t)i * 512 + t4;
    ((float4*)h)[oidx] = acc;
    ((float4*)y)[oidx] = yv;
    // column sums (16 rows in this block)
    __shared__ float ysL[64];
    if (threadIdx.x < 64) ysL[threadIdx.x] = 0.f;
    __syncthreads();
    int c0 = (t4 & 15) * 4;
    atomicAdd(&ysL[c0 + 0], yv.x);
    atomicAdd(&ysL[c0 + 1], yv.y);
    atomicAdd(&ysL[c0 + 2], yv.z);
    atomicAdd(&ysL[c0 + 3], yv.w);
    __syncthreads();
    if (threadIdx.x < 64) atomicAdd(&ysum[b * 64 + threadIdx.x], ysL[threadIdx.x]);
}

// ------ K2: ck (inline from ysum) + qc = (y@Wq)*ck + column max -------------
__global__ void K2(const float* __restrict__ y, const float* __restrict__ wq,
                   const float* __restrict__ wk, const float* __restrict__ ysum,
                   float* __restrict__ qc, unsigned* __restrict__ umax) {
    __shared__ float yT[64][68];      // yT[s][r] = y[t0+r][s], padded
    __shared__ float wqL[64][64];     // wqL[s][c]
    __shared__ float pmax[4][64];
    int b = blockIdx.x, t0 = blockIdx.y * 64;
    int tid = threadIdx.x;
    for (int kk = 0; kk < 16; ++kk) {
        int idx = kk * 256 + tid;
        int r = idx >> 6, cc = idx & 63;
        yT[cc][r] = y[(size_t)b * 131072 + (size_t)(t0 + r) * 64 + cc];
        wqL[r][cc] = wq[(cc >> 3) * 512 + r * 8 + (cc & 7)];
    }
    __syncthreads();
    int c = tid & 63, tq = tid >> 6;
    float ck = 0.f;
    for (int s = 0; s < 64; ++s)
        ck += ysum[b * 64 + s] * wk[(c >> 3) * 512 + s * 8 + (c & 7)];
    float acc[16];
    #pragma unroll
    for (int k = 0; k < 16; ++k) acc[k] = 0.f;
    for (int s = 0; s < 64; ++s) {
        float w = wqL[s][c];
        const float4* yp = (const float4*)&yT[s][tq * 16];
        float4 a0 = yp[0], a1 = yp[1], a2 = yp[2], a3 = yp[3];
        acc[0]  += a0.x * w; acc[1]  += a0.y * w; acc[2]  += a0.z * w; acc[3]  += a0.w * w;
        acc[4]  += a1.x * w; acc[5]  += a1.y * w; acc[6]  += a1.z * w; acc[7]  += a1.w * w;
        acc[8]  += a2.x * w; acc[9]  += a2.y * w; acc[10] += a2.z * w; acc[11] += a2.w * w;
        acc[12] += a3.x * w; acc[13] += a3.y * w; acc[14] += a3.z * w; acc[15] += a3.w * w;
    }
    float lmax = -3.4e38f;
    #pragma unroll
    for (int k = 0; k < 16; ++k) {
        float v = acc[k] * ck;
        qc[(size_t)b * 131072 + (size_t)(t0 + tq * 16 + k) * 64 + c] = v;
        lmax = fmaxf(lmax, v);
    }
    pmax[tq][c] = lmax;
    __syncthreads();
    if (tid < 64) {
        float m = fmaxf(fmaxf(pmax[0][tid], pmax[1][tid]),
                        fmaxf(pmax[2][tid], pmax[3][tid]));
        atomicMax(&umax[b * 64 + tid], fkey(m));
    }
}

// ------ K3: denom[b,c] = sum_t exp(qc - m) ----------------------------------
__global__ void K3(const float* __restrict__ qc, const unsigned* __restrict__ umax,
                   float* __restrict__ denom) {
    __shared__ float psum[4][64];
    int b = blockIdx.x, t0 = blockIdx.y * 64;
    int tid = threadIdx.x, c = tid & 63, tq = tid >> 6;
    float m = fdec(umax[b * 64 + c]);
    float ls = 0.f;
    #pragma unroll 4
    for (int k = 0; k < 16; ++k)
        ls += __expf(qc[(size_t)b * 131072 + (size_t)(t0 + tq * 16 + k) * 64 + c] - m);
    psum[tq][c] = ls;
    __syncthreads();
    if (tid < 64)
        atomicAdd(&denom[b * 64 + tid],
                  psum[0][tid] + psum[1][tid] + psum[2][tid] + psum[3][tid]);
}

// ------ K4: sa=(e*cv/den)@projw+projb; +h; LN2; FFN; + -> hf ---------------
// Block (b,chunk): 8 t-rows, 4 waves x 2 rows. High occupancy (12KiB LDS).
__global__ void K4(const float* __restrict__ h, const float* __restrict__ qc,
                   const float* __restrict__ ysum, const unsigned* __restrict__ umax,
                   const float* __restrict__ denom, const float* __restrict__ wv,
                   const float* __restrict__ projw, const float* __restrict__ projb,
                   const float* __restrict__ g2, const float* __restrict__ b2l,
                   const float* __restrict__ w1, const float* __restrict__ b1,
                   const float* __restrict__ w2, const float* __restrict__ fb2,
                   float* __restrict__ hf) {
    __shared__ float2 pT[4][64];     // pT[w][c] = p rows {0,1} col c
    __shared__ float2 y2T[4][64];
    __shared__ float2 hidT[4][256];
    int b = blockIdx.x, chunk = blockIdx.y;
    int tid = threadIdx.x, l = tid & 63, w = tid >> 6;

    float cv = 0.f;
    for (int s = 0; s < 64; ++s)
        cv += ysum[b * 64 + s] * wv[(l >> 3) * 512 + s * 8 + (l & 7)];
    float m = fdec(umax[b * 64 + l]);
    float scl = cv / denom[b * 64 + l];
    size_t base = (size_t)b * 131072 + (size_t)(chunk * 8 + w * 2) * 64 + l;

    float2 p;
    p.x = __expf(qc[base] - m) * scl;
    p.y = __expf(qc[base + 64] - m) * scl;
    pT[w][l] = p;
    __syncthreads();

    // proj
    float a0 = 0.f, a1 = 0.f;
    for (int c = 0; c < 64; ++c) {
        float2 pv = pT[w][c];
        float pw = projw[c * 64 + l];
        a0 += pv.x * pw; a1 += pv.y * pw;
    }
    float pb = projb[l], g2v = g2[l], b2v = b2l[l];
    float hmid[2], y2[2];
    hmid[0] = h[base] + a0 + pb;
    hmid[1] = h[base + 64] + a1 + pb;
    #pragma unroll
    for (int rr = 0; rr < 2; ++rr) {
        float v = hmid[rr];
        float s1 = v, s2 = v * v;
        for (int off = 32; off; off >>= 1) {
            s1 += __shfl_xor(s1, off);
            s2 += __shfl_xor(s2, off);
        }
        float mm = s1 * (1.f / 64.f);
        float var = s2 * (1.f / 64.f) - mm * mm;
        float rs = rsqrtf(var + EPSF);
        y2[rr] = (v - mm) * rs * g2v + b2v;
    }
    y2T[w][l] = make_float2(y2[0], y2[1]);
    __syncthreads();

    // FFN1: hidden unit u*64+l for rows {0,1}
    float h1[4][2];
    #pragma unroll
    for (int u = 0; u < 4; ++u) {
        float bb = b1[u * 64 + l];
        h1[u][0] = bb; h1[u][1] = bb;
    }
    for (int s = 0; s < 64; ++s) {
        float2 yv = y2T[w][s];
        #pragma unroll
        for (int u = 0; u < 4; ++u) {
            float w1v = w1[s * 256 + u * 64 + l];
            h1[u][0] += yv.x * w1v;
            h1[u][1] += yv.y * w1v;
        }
    }
    #pragma unroll
    for (int u = 0; u < 4; ++u)
        hidT[w][u * 64 + l] = make_float2(fmaxf(h1[u][0], 0.f), fmaxf(h1[u][1], 0.f));
    __syncthreads();

    // FFN2 + residual
    float c0 = 0.f, c1 = 0.f;
    #pragma unroll 4
    for (int jj = 0; jj < 256; ++jj) {
        float2 hv = hidT[w][jj];
        float w2v = w2[jj * 64 + l];
        c0 += hv.x * w2v; c1 += hv.y * w2v;
    }
    float fb = fb2[l];
    hf[base] = hmid[0] + c0 + fb;
    hf[base + 64] = hmid[1] + c1 + fb;
}

// ------ K5: Booster. out[b,i,j,t'] = bw[i,j,t'] * hf[b, j*2048+t'] ----------
// One bw float4 per thread (read once); loop b inside (hf is L2-resident).
__global__ void K5(const float* __restrict__ hf, const float* __restrict__ bw,
                   float* __restrict__ out) {
    int wi = blockIdx.x * 256 + threadIdx.x;    // 0 .. 2M-1 float4 index into bw
    int i = wi >> 15;
    int jt = wi & 32767;                        // j*512 + t4
    const float4* bw4 = (const float4*)bw;
    const float4* hf4 = (const float4*)hf;
    float4* o4 = (float4*)out;
    float4 wv = bw4[wi];
    size_t obase = (size_t)i * 32768 + jt;
    #pragma unroll
    for (int b = 0; b < 4; ++b) {
        float4 hv = hf4[b * 32768 + jt];
        float4 ov;
        ov.x = wv.x * hv.x; ov.y = wv.y * hv.y;
        ov.z = wv.z * hv.z; ov.w = wv.w * hv.w;
        o4[(size_t)b * 2097152 + obase] = ov;
    }
}

extern "C" void kernel_launch(void* const* d_in, const int* in_sizes, int n_in,
                              void* d_out, int out_size, void* d_ws, size_t ws_size,
                              hipStream_t stream) {
    const float* x     = (const float*)d_in[0];
    const float* fw    = (const float*)d_in[1];
    const float* bw    = (const float*)d_in[2];
    const float* wq    = (const float*)d_in[3];
    const float* wk    = (const float*)d_in[4];
    const float* wv    = (const float*)d_in[5];
    const float* projw = (const float*)d_in[6];
    const float* projb = (const float*)d_in[7];
    const float* g1    = (const float*)d_in[8];
    const float* b1l   = (const float*)d_in[9];
    const float* g2    = (const float*)d_in[10];
    const float* b2l   = (const float*)d_in[11];
    const float* w1    = (const float*)d_in[12];
    const float* b1    = (const float*)d_in[13];
    const float* w2    = (const float*)d_in[14];
    const float* b2    = (const float*)d_in[15];
    float* out = (float*)d_out;

    float* wsf = (float*)d_ws;
    float*    h     = wsf;                        // 524288
    float*    y     = wsf + 524288;               // 524288
    float*    qc    = wsf + 1048576;              // 524288
    float*    hf    = wsf + 1572864;              // 524288
    float*    ysum  = wsf + 2097152;              // 256
    unsigned* um    = (unsigned*)(wsf + 2097408); // 256
    float*    denom = wsf + 2097664;              // 256

    hipMemsetAsync(ysum, 0, 768 * sizeof(float), stream);

    K1<<<dim3(256, 2), 256, 0, stream>>>(x, fw, g1, b1l, h, y, ysum);
    K2<<<dim3(4, 32), 256, 0, stream>>>(y, wq, wk, ysum, qc, um);
    K3<<<dim3(4, 32), 256, 0, stream>>>(qc, um, denom);
    K4<<<dim3(4, 256), 256, 0, stream>>>(h, qc, ysum, um, denom, wv, projw, projb,
                                         g2, b2l, w1, b1, w2, b2, hf);
    K5<<<8192, 256, 0, stream>>>(hf, bw, out);
}